// Round 5
// baseline (2273.609 us; speedup 1.0000x reference)
//
#include <hip/hip_runtime.h>
#include <hip/hip_bf16.h>
#include <hip/hip_fp16.h>

// APPNP: h = MLP(x); 10x { h = 0.9 * (D^-1/2 (A+I) D^-1/2) h + 0.1 * h0 }
// R5:
//  - CSR build rework: cross-XCD false sharing on the 4B scatter was the 197MB
//    writeback (record size irrelevant). New: LDS-binned bucketing (dst>>9) with
//    bulk coalesced flushes, then one-block-per-bucket scatter into an
//    L2-resident 64KB csr slice (lines written from ONE XCD, evicted once).
//  - prop_step: paired-edge dword gathers. Lanes 0-31 take edge 2p, lanes 32-63
//    edge 2p+1; each lane loads 4B (2 bf16 feats) -> one instr moves 256B.
//    Halves vmem instr count (theorized limiter) + trims VALU/edge.

typedef __bf16 bf16x8 __attribute__((ext_vector_type(8)));
typedef float f32x4 __attribute__((ext_vector_type(4)));

static constexpr int IN = 512, HID = 256, OUT = 64;
static constexpr int LDT = 40;   // LDS row stride in bf16 elems
static constexpr int BSH = 9;    // bucket = dst >> 9 (512 nodes/bucket, N<=131072)
static constexpr int BINC = 24;  // LDS slots per bucket in fill_bins

static __device__ __forceinline__ ushort f2bf(float f) {
  __hip_bfloat16 b = __float2bfloat16(f);
  return *reinterpret_cast<ushort*>(&b);
}
static __device__ __forceinline__ float bf2f_lo(unsigned int v) {  // low ushort -> f32
  return __uint_as_float(v << 16);
}
static __device__ __forceinline__ float bf2f_hi(unsigned int v) {  // high ushort -> f32
  return __uint_as_float(v & 0xFFFF0000u);
}
// decode low-15-bit fp16 (sign=0) weight
static __device__ __forceinline__ float h15f(unsigned int u) {
  ushort hb = (ushort)(u & 0x7FFFu);
  __half h = *reinterpret_cast<__half*>(&hb);
  return __half2float(h);
}

// ---------------- transpose fp32 [K][C] -> bf16 [C][K] ----------------
__global__ void transpose_f32_bf16(const float* __restrict__ in, ushort* __restrict__ out,
                                   int K, int C) {
  int idx = blockIdx.x * 256 + threadIdx.x;
  if (idx < K * C) {
    int n = idx / K, k = idx % K;
    out[idx] = f2bf(in[k * C + n]);
  }
}

// ---------------- GEMM1: h1 = relu(X @ W1 + b1) ----------------
__global__ __launch_bounds__(256) void gemm1(const float* __restrict__ X,
                                             const ushort* __restrict__ W1T,
                                             const float* __restrict__ b1,
                                             ushort* __restrict__ h1, int M) {
  __shared__ __align__(16) ushort As[128 * LDT];
  __shared__ __align__(16) ushort Bs[128 * LDT];
  const int tid = threadIdx.x;
  const int m0 = blockIdx.x * 128;
  const int n0 = blockIdx.y * 128;
  const int lane = tid & 63, w = tid >> 6;
  const int wr = w >> 1, wc = w & 1;
  const int lm = lane & 15, lq = lane >> 4;
  const int cB = tid & 3, rB = tid >> 2;
  const int cA = tid & 7, rA = tid >> 3;

  f32x4 acc[4][4] = {};

  for (int k0 = 0; k0 < IN; k0 += 32) {
#pragma unroll
    for (int rr = 0; rr < 4; ++rr) {
      int m = rA + rr * 32;
      int gm = m0 + m; gm = gm < M ? gm : M - 1;
      float4 f = *reinterpret_cast<const float4*>(&X[(size_t)gm * IN + k0 + cA * 4]);
      ushort4 cv;
      cv.x = f2bf(f.x); cv.y = f2bf(f.y); cv.z = f2bf(f.z); cv.w = f2bf(f.w);
      *reinterpret_cast<ushort4*>(&As[m * LDT + cA * 4]) = cv;
    }
#pragma unroll
    for (int rr = 0; rr < 2; ++rr) {
      int n = rB + rr * 64;
      *reinterpret_cast<int4*>(&Bs[n * LDT + cB * 8]) =
          *reinterpret_cast<const int4*>(&W1T[(size_t)(n0 + n) * IN + k0 + cB * 8]);
    }
    __syncthreads();
    bf16x8 af[4], bq[4];
#pragma unroll
    for (int mi = 0; mi < 4; ++mi)
      af[mi] = *reinterpret_cast<const bf16x8*>(&As[(wr * 64 + mi * 16 + lm) * LDT + lq * 8]);
#pragma unroll
    for (int ni = 0; ni < 4; ++ni)
      bq[ni] = *reinterpret_cast<const bf16x8*>(&Bs[(wc * 64 + ni * 16 + lm) * LDT + lq * 8]);
#pragma unroll
    for (int mi = 0; mi < 4; ++mi)
#pragma unroll
      for (int ni = 0; ni < 4; ++ni)
        acc[mi][ni] = __builtin_amdgcn_mfma_f32_16x16x32_bf16(af[mi], bq[ni], acc[mi][ni], 0, 0, 0);
    __syncthreads();
  }

#pragma unroll
  for (int ni = 0; ni < 4; ++ni) {
    int col = n0 + wc * 64 + ni * 16 + lm;
    float bias = b1[col];
#pragma unroll
    for (int mi = 0; mi < 4; ++mi) {
#pragma unroll
      for (int rg = 0; rg < 4; ++rg) {
        int row = m0 + wr * 64 + mi * 16 + lq * 4 + rg;
        if (row < M) {
          float v = acc[mi][ni][rg] + bias;
          v = v > 0.f ? v : 0.f;
          h1[(size_t)row * HID + col] = f2bf(v);
        }
      }
    }
  }
}

// ---------------- GEMM2: H0 = h1 @ W2 + b2, fp32 + bf16 mirror out ----------------
__global__ __launch_bounds__(256) void gemm2(const ushort* __restrict__ h1,
                                             const ushort* __restrict__ W2T,
                                             const float* __restrict__ b2,
                                             float* __restrict__ H0f,
                                             ushort* __restrict__ H0b, int M) {
  __shared__ __align__(16) ushort As[128 * LDT];
  __shared__ __align__(16) ushort Bs[64 * LDT];
  const int tid = threadIdx.x;
  const int m0 = blockIdx.x * 128;
  const int lane = tid & 63, w = tid >> 6;
  const int lm = lane & 15, lq = lane >> 4;
  const int c = tid & 3, r = tid >> 2;

  f32x4 acc[2][4] = {};

  for (int k0 = 0; k0 < HID; k0 += 32) {
#pragma unroll
    for (int rr = 0; rr < 2; ++rr) {
      int m = r + rr * 64;
      int gm = m0 + m; gm = gm < M ? gm : M - 1;
      *reinterpret_cast<int4*>(&As[m * LDT + c * 8]) =
          *reinterpret_cast<const int4*>(&h1[(size_t)gm * HID + k0 + c * 8]);
    }
    *reinterpret_cast<int4*>(&Bs[r * LDT + c * 8]) =
        *reinterpret_cast<const int4*>(&W2T[(size_t)r * HID + k0 + c * 8]);
    __syncthreads();
    bf16x8 af[2], bq[4];
#pragma unroll
    for (int mi = 0; mi < 2; ++mi)
      af[mi] = *reinterpret_cast<const bf16x8*>(&As[(w * 32 + mi * 16 + lm) * LDT + lq * 8]);
#pragma unroll
    for (int ni = 0; ni < 4; ++ni)
      bq[ni] = *reinterpret_cast<const bf16x8*>(&Bs[(ni * 16 + lm) * LDT + lq * 8]);
#pragma unroll
    for (int mi = 0; mi < 2; ++mi)
#pragma unroll
      for (int ni = 0; ni < 4; ++ni)
        acc[mi][ni] = __builtin_amdgcn_mfma_f32_16x16x32_bf16(af[mi], bq[ni], acc[mi][ni], 0, 0, 0);
    __syncthreads();
  }

#pragma unroll
  for (int ni = 0; ni < 4; ++ni) {
    int col = ni * 16 + lm;
    float bias = b2[col];
#pragma unroll
    for (int mi = 0; mi < 2; ++mi) {
#pragma unroll
      for (int rg = 0; rg < 4; ++rg) {
        int row = m0 + w * 32 + mi * 16 + lq * 4 + rg;
        if (row < M) {
          float v = acc[mi][ni][rg] + bias;
          H0f[(size_t)row * OUT + col] = v;
          H0b[(size_t)row * OUT + col] = f2bf(v);
        }
      }
    }
  }
}

// ---------------- degree + bucket counts ----------------
__global__ __launch_bounds__(256) void deg_bucket(const int* __restrict__ ei,
                                                  int* __restrict__ cnt,
                                                  int* __restrict__ bcnt, int E) {
  __shared__ int lb[256];
  int t = threadIdx.x;
  lb[t] = 0;
  __syncthreads();
  int e = blockIdx.x * 1024 + t;
#pragma unroll
  for (int k = 0; k < 4; ++k) {
    if (e < E) {
      int d = ei[E + e];
      atomicAdd(&cnt[d], 1);
      atomicAdd(&lb[d >> BSH], 1);
    }
    e += 256;
  }
  __syncthreads();
  if (lb[t]) atomicAdd(&bcnt[t], lb[t]);
}

__global__ void calc_dinv(const int* __restrict__ cnt, float* __restrict__ dinv, int n) {
  int v = blockIdx.x * 256 + threadIdx.x;
  if (v < n) dinv[v] = rsqrtf((float)cnt[v] + 1.0f);  // +1: self-loop
}

// scan of 256 bucket counts -> boff[257], bcur[256]
__global__ __launch_bounds__(256) void bucket_scan(const int* __restrict__ bcnt,
                                                   int* __restrict__ boff,
                                                   int* __restrict__ bcur) {
  __shared__ int ws[4];
  int t = threadIdx.x, lane = t & 63, wid = t >> 6;
  int x = bcnt[t];
  int v = x;
#pragma unroll
  for (int d = 1; d < 64; d <<= 1) {
    int tt = __shfl_up(v, d, 64);
    if (lane >= d) v += tt;
  }
  if (lane == 63) ws[wid] = v;
  __syncthreads();
  int off = 0;
  for (int i = 0; i < wid; ++i) off += ws[i];
  int excl = off + v - x;
  boff[t] = excl;
  bcur[t] = excl;
  if (t == 255) boff[256] = excl + x;
}

// single-block exclusive scan of cnt[n] -> offs[n+1], cursor[n]; 8 elems/thread/iter
__global__ __launch_bounds__(1024) void scan_kernel(const int* __restrict__ cnt,
                                                    int* __restrict__ offs,
                                                    int* __restrict__ cursor, int n) {
  __shared__ int wsum[16];
  __shared__ int woff[16];
  __shared__ int carry_s;
  const int tid = threadIdx.x;
  const int lane = tid & 63, wid = tid >> 6;
  if (tid == 0) carry_s = 0;
  __syncthreads();
  for (int base = 0; base < n; base += 8192) {
    int i0 = base + tid * 8;
    int x[8];
#pragma unroll
    for (int j = 0; j < 8; ++j) x[j] = (i0 + j < n) ? cnt[i0 + j] : 0;
    int tsum = 0;
#pragma unroll
    for (int j = 0; j < 8; ++j) tsum += x[j];
    int val = tsum;
#pragma unroll
    for (int d = 1; d < 64; d <<= 1) {
      int t = __shfl_up(val, d, 64);
      if (lane >= d) val += t;
    }
    if (lane == 63) wsum[wid] = val;
    __syncthreads();
    if (wid == 0) {
      int s = (lane < 16) ? wsum[lane] : 0;
      int sv = s;
#pragma unroll
      for (int d = 1; d < 16; d <<= 1) {
        int t = __shfl_up(sv, d, 64);
        if (lane >= d) sv += t;
      }
      if (lane < 16) woff[lane] = sv - s;
    }
    __syncthreads();
    int excl = carry_s + woff[wid] + (val - tsum);
#pragma unroll
    for (int j = 0; j < 8; ++j) {
      if (i0 + j < n) { offs[i0 + j] = excl; cursor[i0 + j] = excl; }
      excl += x[j];
    }
    __syncthreads();
    if (tid == 1023) carry_s = excl;
    __syncthreads();
  }
  if (tid == 0) offs[n] = carry_s;
}

// ---------------- binned edge bucketing ----------------
// Tile of 2048 edges per block; LDS append per bucket; bulk coalesced flush.
// Record: .x = dst, .y = (src<<15)|fp16bits(w)
__global__ __launch_bounds__(256) void fill_bins(const int* __restrict__ ei,
                                                 const float* __restrict__ dinv,
                                                 int* __restrict__ bcur,
                                                 int2* __restrict__ bed, int E) {
  __shared__ int2 buf[256][BINC];  // 48 KB
  __shared__ int lbc[256];
  const int t = threadIdx.x;
  const int base = blockIdx.x * 2048;
  lbc[t] = 0;
  __syncthreads();
#pragma unroll
  for (int k = 0; k < 8; ++k) {
    int e = base + k * 256 + t;
    if (e < E) {
      int s = ei[e], d = ei[E + e];
      float w = dinv[s] * dinv[d];
      __half hw = __float2half(w);
      unsigned int packed = (((unsigned int)s) << 15) | *reinterpret_cast<ushort*>(&hw);
      int b = d >> BSH;
      int slot = atomicAdd(&lbc[b], 1);
      if (slot < BINC) {
        buf[b][slot] = make_int2(d, (int)packed);
      } else {  // rare overflow: direct (slow) path
        int p = atomicAdd(&bcur[b], 1);
        bed[p] = make_int2(d, (int)packed);
      }
    }
  }
  __syncthreads();
  const int lane = t & 63, wid = t >> 6;
  for (int b = wid; b < 256; b += 4) {
    int c = lbc[b];
    if (c > BINC) c = BINC;
    if (c == 0) continue;
    int gbase;
    if (lane == 0) gbase = atomicAdd(&bcur[b], c);
    gbase = __shfl(gbase, 0);
    if (lane < c) bed[gbase + lane] = buf[b][lane];
  }
}

// one block per bucket: scatter into the bucket's L2-resident csr slice
__global__ __launch_bounds__(256) void csr_scatter(const int2* __restrict__ bed,
                                                   const int* __restrict__ boff,
                                                   int* __restrict__ curs,
                                                   unsigned int* __restrict__ csr) {
  int b = blockIdx.x;
  int s = boff[b], e = boff[b + 1];
  for (int i = s + threadIdx.x; i < e; i += 256) {
    int2 r = bed[i];
    int p = atomicAdd(&curs[r.x], 1);
    csr[p] = (unsigned int)r.y;
  }
}

// ---------------- propagation: paired-edge dword gathers ----------------
// Wave per node. Lanes 0-31 handle even edges of each pair, 32-63 odd.
// Each lane loads a dword = 2 bf16 features; combine halves via shfl_xor(32).
template <bool WRITE_BF>
__global__ __launch_bounds__(256) void prop_step(const float* __restrict__ hinf,
                                                 const ushort* __restrict__ hinb,
                                                 float* __restrict__ houtf,
                                                 ushort* __restrict__ houtb,
                                                 const float* __restrict__ h0,
                                                 const int* __restrict__ offs,
                                                 const unsigned int* __restrict__ csr,
                                                 const float* __restrict__ dinv, int n) {
  const int gw = (blockIdx.x * 256 + threadIdx.x) >> 6;
  const int lane = threadIdx.x & 63;
  if (gw >= n) return;
  const int half = lane >> 5, col = lane & 31;
  const unsigned int* hin32 = reinterpret_cast<const unsigned int*>(hinb);

  float ax[4] = {0.f, 0.f, 0.f, 0.f};
  float ay[4] = {0.f, 0.f, 0.f, 0.f};
  int e0 = offs[gw], e1 = offs[gw + 1];
  for (int base = e0; base < e1; base += 64) {
    int rem = e1 - base;
    unsigned int my = (lane < rem) ? csr[base + lane] : 0u;  // pad: src=0,w=+0
    int cnt = rem < 64 ? rem : 64;
    int cnt16 = (cnt + 15) & ~15;
    for (int j = 0; j < cnt16; j += 16) {  // 8 pairs = 16 edges in flight
      unsigned int u[8];
#pragma unroll
      for (int p = 0; p < 8; ++p)
        u[p] = (unsigned int)__shfl((int)my, j + 2 * p + half);  // bpermute
      unsigned int v[8];
#pragma unroll
      for (int p = 0; p < 8; ++p)
        v[p] = hin32[(size_t)(u[p] >> 15) * 32 + col];
#pragma unroll
      for (int p = 0; p < 8; ++p) {
        float w = h15f(u[p]);
        ax[p & 3] = fmaf(w, bf2f_lo(v[p]), ax[p & 3]);
        ay[p & 3] = fmaf(w, bf2f_hi(v[p]), ay[p & 3]);
      }
    }
  }
  float tx = (ax[0] + ax[1]) + (ax[2] + ax[3]);
  float ty = (ay[0] + ay[1]) + (ay[2] + ay[3]);
  tx += __shfl_xor(tx, 32);
  ty += __shfl_xor(ty, 32);

  // epilogue on lanes 0-31: features (2*col, 2*col+1)
  float dv = dinv[gw];
  float2 sv = *reinterpret_cast<const float2*>(&hinf[(size_t)gw * OUT + 2 * col]);
  float2 hv = *reinterpret_cast<const float2*>(&h0[(size_t)gw * OUT + 2 * col]);
  float ox = 0.9f * (tx + sv.x * dv * dv) + 0.1f * hv.x;
  float oy = 0.9f * (ty + sv.y * dv * dv) + 0.1f * hv.y;
  if (lane < 32) {
    *reinterpret_cast<float2*>(&houtf[(size_t)gw * OUT + 2 * col]) = make_float2(ox, oy);
    if (WRITE_BF) {
      unsigned int pk = (unsigned int)f2bf(ox) | ((unsigned int)f2bf(oy) << 16);
      reinterpret_cast<unsigned int*>(houtb)[(size_t)gw * 32 + col] = pk;
    }
  }
}

extern "C" void kernel_launch(void* const* d_in, const int* in_sizes, int n_in,
                              void* d_out, int out_size, void* d_ws, size_t ws_size,
                              hipStream_t stream) {
  const float* X  = (const float*)d_in[0];  // [N,512] f32
  const int*   EI = (const int*)d_in[1];    // [2,E] int32
  const float* W1 = (const float*)d_in[2];  // [512,256] f32
  const float* b1 = (const float*)d_in[3];  // [256] f32
  const float* W2 = (const float*)d_in[4];  // [256,64] f32
  const float* b2 = (const float*)d_in[5];  // [64] f32
  float* out = (float*)d_out;               // [N,64] f32

  const int N = in_sizes[0] / IN;  // 100000
  const int E = in_sizes[1] / 2;   // 3200000

  char* ws = (char*)d_ws;
  size_t o = 0;
  auto alloc = [&](size_t b) {
    char* p = ws + o;
    o = (o + b + 255) & ~(size_t)255;
    return p;
  };
  float*  H0f  = (float*)alloc((size_t)N * OUT * 4);
  ushort* H0b  = (ushort*)alloc((size_t)N * OUT * 2);
  float*  hAf  = (float*)alloc((size_t)N * OUT * 4);
  ushort* hAb  = (ushort*)alloc((size_t)N * OUT * 2);
  float*  hBf  = (float*)alloc((size_t)N * OUT * 4);
  ushort* hBb  = (ushort*)alloc((size_t)N * OUT * 2);
  ushort* h1   = (ushort*)alloc((size_t)N * HID * 2);
  ushort* W1T  = (ushort*)alloc((size_t)IN * HID * 2);
  ushort* W2T  = (ushort*)alloc((size_t)HID * OUT * 2);
  int*    cnt  = (int*)alloc((size_t)N * 4);
  int*    offs = (int*)alloc((size_t)(N + 1) * 4);
  int*    curs = (int*)alloc((size_t)N * 4);
  float*  dinv = (float*)alloc((size_t)N * 4);
  int*    bcnt = (int*)alloc(256 * 4);
  int*    boff = (int*)alloc(257 * 4);
  int*    bcur = (int*)alloc(256 * 4);
  int2*   bed  = (int2*)alloc((size_t)E * 8);
  unsigned int* csr = (unsigned int*)alloc((size_t)E * 4);
  (void)ws_size; (void)n_in; (void)out_size;

  transpose_f32_bf16<<<(IN * HID + 255) / 256, 256, 0, stream>>>(W1, W1T, IN, HID);
  transpose_f32_bf16<<<(HID * OUT + 255) / 256, 256, 0, stream>>>(W2, W2T, HID, OUT);

  gemm1<<<dim3((N + 127) / 128, HID / 128), 256, 0, stream>>>(X, W1T, b1, h1, N);
  gemm2<<<(N + 127) / 128, 256, 0, stream>>>(h1, W2T, b2, H0f, H0b, N);

  hipMemsetAsync(cnt, 0, (size_t)N * 4, stream);
  hipMemsetAsync(bcnt, 0, 256 * 4, stream);
  deg_bucket<<<(E + 1023) / 1024, 256, 0, stream>>>(EI, cnt, bcnt, E);
  calc_dinv<<<(N + 255) / 256, 256, 0, stream>>>(cnt, dinv, N);
  bucket_scan<<<1, 256, 0, stream>>>(bcnt, boff, bcur);
  scan_kernel<<<1, 1024, 0, stream>>>(cnt, offs, curs, N);
  fill_bins<<<(E + 2047) / 2048, 256, 0, stream>>>(EI, dinv, bcur, bed, E);
  csr_scatter<<<256, 256, 0, stream>>>(bed, boff, curs, csr);

  const int pgrid = (N * OUT + 255) / 256;  // one wave per node
  prop_step<true><<<pgrid, 256, 0, stream>>>(H0f, H0b, hAf, hAb, H0f, offs, csr, dinv, N);
  for (int i = 0; i < 4; ++i) {
    prop_step<true><<<pgrid, 256, 0, stream>>>(hAf, hAb, hBf, hBb, H0f, offs, csr, dinv, N);
    prop_step<true><<<pgrid, 256, 0, stream>>>(hBf, hBb, hAf, hAb, H0f, offs, csr, dinv, N);
  }
  prop_step<false><<<pgrid, 256, 0, stream>>>(hAf, hAb, out, nullptr, H0f, offs, csr, dinv, N);
}